// Round 5
// baseline (598.687 us; speedup 1.0000x reference)
//
#include <hip/hip_runtime.h>

// Problem constants: B=64, C=256, H=W=28, N=784
#define BB   64
#define CC   256
#define NPIX 784
#define SLOTS 128
#define SSTR 260   // slab row stride (floats); 16B-aligned fragments

// ---------------------------------------------------------------------------
// Fused masked-cosine-sim kernel, R4.
// R3 confirmed the traffic model (FETCH 100.5 MB = y+z once, XCD-pinned L2)
// but ran 1 block/CU (77 KB LDS) and latency-stalled (VALUBusy 32%).
// R4: (a) ylds removed -> y fragments live in registers, LDS = 62.8 KB ->
// 2 blocks/CU = 28 waves; (b) staging restructured lane<->slot, wave<->
// channel-stride: no div/mod, 1 load + 1 LDS write per element.
// Mask math, dot FMA chains, slab geometry, norm order: byte-identical
// to the R3-verified kernel (absmax was 0.0).
// ---------------------------------------------------------------------------
__global__ __launch_bounds__(896, 8) void pairs_k(
    const float* __restrict__ y1, const float* __restrict__ y2,
    const float* __restrict__ z1, const float* __restrict__ z2,
    const float* __restrict__ g1g, const float* __restrict__ g2g,
    double* __restrict__ acc) {
    __shared__ float  slab[60 * SSTR];  // [slot s = ry*20+k][c]
    __shared__ float  nlds[60];         // per-slot z squared-norms
    __shared__ double shs[14];
    __shared__ int    shc[14];

    int tid  = threadIdx.x;
    int lane = tid & 63, wv = tid >> 6;     // wv 0..13, wave per i
    int bid  = blockIdx.x;
    int xcd  = bid & 7;
    int q    = bid >> 3;                    // 0..895
    int loss = q / 448;
    int rr   = q - loss * 448;              // 0..447
    int b8   = rr / 56;
    int tile = rr - b8 * 56;                // 0..55
    int b    = xcd + 8 * b8;
    int row  = tile >> 1, hf = tile & 1;
    int i0   = row * 28 + 14 * hf;          // first of 14 i's

    const float* g1 = g1g + (size_t)b * 2 * NPIX;
    const float* g2 = g2g + (size_t)b * 2 * NPIX;

    // ---- block-uniform box params (bit-exact same chain as per-i mask) ----
    const float* gb = loss ? g2 : g1;
    float d0  = gb[29] - gb[0];
    float d1  = gb[NPIX + 29] - gb[NPIX];
    float bin = __fsqrt_rn(__fadd_rn(__fmul_rn(d0, d0), __fmul_rn(d1, d1)));
    float t2y = g2[0], t2x = g2[NPIX];
    float s2y = g2[28] - g2[0];
    float s2x = g2[NPIX + 1] - g2[NPIX];
    float rV  = 0.7f * bin * 1.0002f + 1e-4f;
    float ryr = rV / s2y + 0.05f;
    float rxr = rV / s2x + 0.05f;
    float cy0 = (g1[i0] - t2y) / s2y;            // same float for all i in row
    int JR0 = max(0, (int)ceilf(cy0 - ryr));     // == every i's jy0
    float cxf = (g1[NPIX + i0] - t2x) / s2x;
    int JCL = max(0, (int)ceilf(cxf - rxr));     // == min over i of jx0

    // ---- y fragments straight to registers (issue early, hide latency) ----
    int i  = i0 + wv;
    int gl = lane & 15, g = lane >> 4;
    const float* Yg = (loss ? y2 : y1) + (size_t)b * CC * NPIX;
    const float* yp = Yg + (size_t)(4 * gl) * NPIX + i;
    float4 ya, yb, yc, yd;
    ya.x = yp[(size_t)0 * NPIX];   ya.y = yp[(size_t)1 * NPIX];
    ya.z = yp[(size_t)2 * NPIX];   ya.w = yp[(size_t)3 * NPIX];
    yb.x = yp[(size_t)64 * NPIX];  yb.y = yp[(size_t)65 * NPIX];
    yb.z = yp[(size_t)66 * NPIX];  yb.w = yp[(size_t)67 * NPIX];
    yc.x = yp[(size_t)128 * NPIX]; yc.y = yp[(size_t)129 * NPIX];
    yc.z = yp[(size_t)130 * NPIX]; yc.w = yp[(size_t)131 * NPIX];
    yd.x = yp[(size_t)192 * NPIX]; yd.y = yp[(size_t)193 * NPIX];
    yd.z = yp[(size_t)194 * NPIX]; yd.w = yp[(size_t)195 * NPIX];

    // ---- stage slab: lane = slot (0..59), wave strides channels ----
    const float* Zb = (loss ? z1 : z2) + (size_t)b * CC * NPIX;
    if (lane < 60) {
        int s  = lane;
        int ry = (s >= 40) ? 2 : ((s >= 20) ? 1 : 0);
        int k  = s - ry * 20;
        int jr = min(JR0 + ry, 27);
        int jc = min(JCL + k, 27);
        const float* zp = Zb + (size_t)wv * NPIX + jr * 28 + jc;
        float* dst = slab + s * SSTR + wv;
        for (int c = wv; c < 256; c += 14) {
            *dst = *zp;
            zp  += (size_t)14 * NPIX;
            dst += 14;
        }
    }

    // ---- per-wave mask (byte-identical to verified kernel) ----
    float g1y = g1[i];
    float g1x = g1[NPIX + i];
    float cy = (g1y - t2y) / s2y;
    float cx = (g1x - t2x) / s2x;
    int jy0 = max(0,  (int)ceilf(cy - ryr));
    int jy1 = min(27, (int)floorf(cy + ryr));
    int jx0 = max(0,  (int)ceilf(cx - rxr));
    int jx1 = min(27, (int)floorf(cx + rxr));
    int dyr = jy1 - jy0, dxr = jx1 - jx0;

    int dyl = lane >> 2, dxl = lane & 3;
    bool pass = false;
    if (lane < 16 && dyl <= dyr && dxl <= dxr) {
        int jc2 = (jy0 + dyl) * 28 + jx0 + dxl;
        float dy = g1y - g2[jc2];
        float dx = g1x - g2[NPIX + jc2];
        float d  = __fsqrt_rn(__fadd_rn(__fmul_rn(dy, dy), __fmul_rn(dx, dx)));
        pass = (__fdiv_rn(d, bin) <= 0.7f);   // bit-exact mask decision
    }
    unsigned long long mball = __ballot(pass);
    int cnt = __builtin_popcountll(mball);

    __syncthreads();

    // ---- per-slot z norms (16-lane group per slot, 56 groups for 60) ----
    {
        int gid = wv * 4 + (lane >> 4);       // 0..55
        int gl2 = lane & 15;
        for (int s = gid; s < 60; s += 56) {
            const float4* Z4 = (const float4*)(slab + s * SSTR);
            float4 a = Z4[gl2], b4 = Z4[gl2 + 16], c4 = Z4[gl2 + 32], e4 = Z4[gl2 + 48];
            float pp = a.x * a.x;
            pp = fmaf(a.y, a.y, pp); pp = fmaf(a.z, a.z, pp); pp = fmaf(a.w, a.w, pp);
            pp = fmaf(b4.x, b4.x, pp); pp = fmaf(b4.y, b4.y, pp); pp = fmaf(b4.z, b4.z, pp);
            pp = fmaf(b4.w, b4.w, pp);
            pp = fmaf(c4.x, c4.x, pp); pp = fmaf(c4.y, c4.y, pp); pp = fmaf(c4.z, c4.z, pp);
            pp = fmaf(c4.w, c4.w, pp);
            pp = fmaf(e4.x, e4.x, pp); pp = fmaf(e4.y, e4.y, pp); pp = fmaf(e4.z, e4.z, pp);
            pp = fmaf(e4.w, e4.w, pp);
#pragma unroll
            for (int off = 1; off < 16; off <<= 1) pp += __shfl_xor(pp, off);
            if (gl2 == 0) nlds[s] = pp;
        }
    }
    __syncthreads();

    // ---- na from register fragments (16-lane group reduce) ----
    float p = ya.x * ya.x;
    p = fmaf(ya.y, ya.y, p); p = fmaf(ya.z, ya.z, p); p = fmaf(ya.w, ya.w, p);
    p = fmaf(yb.x, yb.x, p); p = fmaf(yb.y, yb.y, p); p = fmaf(yb.z, yb.z, p);
    p = fmaf(yb.w, yb.w, p);
    p = fmaf(yc.x, yc.x, p); p = fmaf(yc.y, yc.y, p); p = fmaf(yc.z, yc.z, p);
    p = fmaf(yc.w, yc.w, p);
    p = fmaf(yd.x, yd.x, p); p = fmaf(yd.y, yd.y, p); p = fmaf(yd.z, yd.z, p);
    p = fmaf(yd.w, yd.w, p);
#pragma unroll
    for (int off = 1; off < 16; off <<= 1) p += __shfl_xor(p, off);
    float na = __fsqrt_rn(p);

    // ---- compact-slot dot rounds (structure identical to verified R2/R3) ----
    int off_i = jx0 - JCL;                    // >= 0 by monotonicity
    unsigned mm = (unsigned)mball;
    if (g > 0) mm &= mm - 1;
    if (g > 1) mm &= mm - 1;
    if (g > 2) mm &= mm - 1;
    int rounds = (cnt + 3) >> 2;

    double ssum = 0.0;
    for (int r2 = 0; r2 < rounds; r2++) {
        bool val = (mm != 0);
        int s  = val ? (__ffs(mm) - 1) : 0;
        int sl = val ? ((s >> 2) * 20 + off_i + (s & 3)) : 0;
        const float4* Z4 = (const float4*)(slab + sl * SSTR);
        float4 za = Z4[gl], zb_ = Z4[gl + 16], zc = Z4[gl + 32], zd = Z4[gl + 48];
        float nb2 = nlds[sl];
        float dp = ya.x * za.x;
        dp = fmaf(ya.y, za.y, dp); dp = fmaf(ya.z, za.z, dp);
        dp = fmaf(ya.w, za.w, dp);
        dp = fmaf(yb.x, zb_.x, dp); dp = fmaf(yb.y, zb_.y, dp);
        dp = fmaf(yb.z, zb_.z, dp); dp = fmaf(yb.w, zb_.w, dp);
        dp = fmaf(yc.x, zc.x, dp); dp = fmaf(yc.y, zc.y, dp);
        dp = fmaf(yc.z, zc.z, dp); dp = fmaf(yc.w, zc.w, dp);
        dp = fmaf(yd.x, zd.x, dp); dp = fmaf(yd.y, zd.y, dp);
        dp = fmaf(yd.z, zd.z, dp); dp = fmaf(yd.w, zd.w, dp);
#pragma unroll
        for (int off = 1; off < 16; off <<= 1) dp += __shfl_xor(dp, off);
        float den = fmaxf(na * __fsqrt_rn(nb2), 1e-8f);
        float sim = __fdividef(dp, den);
        if (val) ssum += (double)sim;
        mm &= mm - 1; mm &= mm - 1; mm &= mm - 1; mm &= mm - 1;
    }
    ssum += __shfl_xor(ssum, 16);
    ssum += __shfl_xor(ssum, 32);

    if (lane == 0) { shs[wv] = ssum; shc[wv] = cnt; }
    __syncthreads();
    if (tid == 0) {
        double s = 0.0; int c = 0;
#pragma unroll
        for (int k = 0; k < 14; k++) { s += shs[k]; c += shc[k]; }
        double* slot = acc + (size_t)(bid & (SLOTS - 1)) * 4;
        atomicAdd(&slot[loss * 2],     s);
        atomicAdd(&slot[loss * 2 + 1], (double)c);
    }
}

// ---------------------------------------------------------------------------
// finalize  loss = -(S0/M0 + S1/M1)  (reduce the 128 slots)
// ---------------------------------------------------------------------------
__global__ void fin_k(const double* __restrict__ acc, float* __restrict__ out) {
    int lane = threadIdx.x;   // 64 threads
    double s0 = 0, m0 = 0, s1 = 0, m1 = 0;
    for (int s = lane; s < SLOTS; s += 64) {
        const double* p = acc + (size_t)s * 4;
        s0 += p[0]; m0 += p[1]; s1 += p[2]; m1 += p[3];
    }
#pragma unroll
    for (int off = 32; off; off >>= 1) {
        s0 += __shfl_xor(s0, off); m0 += __shfl_xor(m0, off);
        s1 += __shfl_xor(s1, off); m1 += __shfl_xor(m1, off);
    }
    if (lane == 0) out[0] = (float)(-(s0 / m0 + s1 / m1));
}

extern "C" void kernel_launch(void* const* d_in, const int* in_sizes, int n_in,
                              void* d_out, int out_size, void* d_ws, size_t ws_size,
                              hipStream_t stream) {
    const float* y1 = (const float*)d_in[0];
    const float* y2 = (const float*)d_in[1];
    const float* z1 = (const float*)d_in[2];
    const float* z2 = (const float*)d_in[3];
    const float* g1 = (const float*)d_in[4];
    const float* g2 = (const float*)d_in[5];
    float* out = (float*)d_out;

    double* acc = (double*)d_ws;              // SLOTS*4 doubles = 4 KB
    hipMemsetAsync(acc, 0, SLOTS * 4 * sizeof(double), stream);

    // fused: 8 xcd * 2 loss * 8 b8 * 56 tiles = 7168 blocks x 896 threads
    pairs_k<<<7168, 896, 0, stream>>>(y1, y2, z1, z2, g1, g2, acc);

    fin_k<<<1, 64, 0, stream>>>(acc, out);
}

// Round 6
// 267.345 us; speedup vs baseline: 2.2394x; 2.2394x over previous
//
#include <hip/hip_runtime.h>
#include <hip/hip_bf16.h>

// Problem constants: B=64, C=256, H=W=28, N=784
#define BB   64
#define CC   256
#define NPIX 784
#define BNP  (BB * NPIX)   // 50176
#define SLOTS 128

// ---------------------------------------------------------------------------
// K1: transpose z1,z2 [B,C,N] -> zt[2,B,N,C] + fused squared norms.
// (verified in the 267.5 us run; unchanged)
// ---------------------------------------------------------------------------
__global__ __launch_bounds__(512, 8) void zt_k(
    const float* __restrict__ z1, const float* __restrict__ z2,
    float* __restrict__ zt, float* __restrict__ zn2) {
    __shared__ float lds[32 * 257];
    __shared__ float part[16][32];

    int bx = blockIdx.x;
    int nt = bx % 25;
    int t  = bx / 25;
    int b  = t & 63;
    int arr = t >> 6;                       // 0 = z1, 1 = z2
    int nlim = (nt == 24) ? 16 : 32;        // 24*32 + 16 = 784

    const float* in = (arr ? z2 : z1) + (size_t)b * CC * NPIX + nt * 32;
    int tid  = threadIdx.x;
    int n4   = tid & 7;                     // float4 index along n
    int subc = tid >> 3;                    // 0..63
    int nn   = 4 * n4;

    // stage: coalesced float4 along n; scatter scalars to [n][c]
#pragma unroll
    for (int k = 0; k < 4; k++) {
        int c = subc + 64 * k;
        float4 v = {0.f, 0.f, 0.f, 0.f};
        if (nn < nlim) v = *(const float4*)(in + (size_t)c * NPIX + nn);
        lds[(nn + 0) * 257 + c] = v.x;
        lds[(nn + 1) * 257 + c] = v.y;
        lds[(nn + 2) * 257 + c] = v.z;
        lds[(nn + 3) * 257 + c] = v.w;
    }
    __syncthreads();

    // squared-norm partials: thread (nl, cq) sums 16 channels
    {
        int nl = tid & 31, cq = tid >> 5;   // cq 0..15
        float s = 0.f;
#pragma unroll
        for (int sc = 0; sc < 16; sc++) {
            float v = lds[nl * 257 + cq * 16 + sc];
            s = fmaf(v, v, s);
        }
        part[cq][nl] = s;
    }

    // transposed write: 16 consecutive lanes write 256 B contiguous
    float* outb = zt + ((size_t)arr * BB + b) * ((size_t)NPIX * CC)
                     + (size_t)nt * 32 * CC;
    int lane = tid & 63, wv = tid >> 6;     // wv 0..7
    int c4 = lane & 15, nq = (lane >> 4) & 3;
    int n = 4 * wv + nq;
    if (n < nlim) {
#pragma unroll
        for (int cq2 = 0; cq2 < 4; cq2++) {
            int cc0 = 64 * cq2 + 4 * c4;
            float4 v;
            v.x = lds[n * 257 + cc0 + 0];
            v.y = lds[n * 257 + cc0 + 1];
            v.z = lds[n * 257 + cc0 + 2];
            v.w = lds[n * 257 + cc0 + 3];
            *(float4*)(outb + (size_t)n * CC + cc0) = v;
        }
    }
    __syncthreads();
    if (tid < nlim) {
        float s = 0.f;
#pragma unroll
        for (int k = 0; k < 16; k++) s += part[k][tid];
        zn2[(size_t)arr * BNP + (size_t)b * NPIX + nt * 32 + tid] = s;
    }
}

// ---------------------------------------------------------------------------
// K2: masked pair cosine sims. Block = (loss, b, 16 consecutive i),
// 1024 threads = 16 waves, wave per i. Identical to the verified 267.5-us
// kernel EXCEPT the round loop: deferred-division accumulation.
//   sim = (sum_l dp_l)/den = sum_l (dp_l/den)   (den is lane-uniform)
// -> per-lane double accumulator, ONE 64-lane butterfly at the end instead
// of a 4-step shuffle chain per round; invalid groups (mm==0) now skip the
// whole body under exec-mask (no dummy j=0 row loads).
// ---------------------------------------------------------------------------
__global__ __launch_bounds__(1024, 8) void pairs_k(
    const float* __restrict__ y1, const float* __restrict__ y2,
    const float* __restrict__ zt, const float* __restrict__ zn2,
    const float* __restrict__ g1g, const float* __restrict__ g2g,
    double* __restrict__ acc) {
    __shared__ float  ylds[16 * 256];     // [i][c]
    __shared__ double shs[16];
    __shared__ int    shc[16];

    int tid  = threadIdx.x;
    int lane = tid & 63, wv = tid >> 6;
    int bx   = blockIdx.x;                   // [0, 6272)
    int loss = (bx >= 3136) ? 1 : 0;
    int rem  = bx - loss * 3136;
    int b    = rem / 49;
    int ig   = rem - b * 49;
    int i0   = 16 * ig;

    // stage y[b, :, i0..i0+15]: thread c<256 reads the full 64B line
    const float* Yg = (loss ? y2 : y1) + (size_t)b * CC * NPIX;
    if (tid < 256) {
        const float* row = Yg + (size_t)tid * NPIX + i0;
#pragma unroll
        for (int q = 0; q < 4; q++) {
            float4 v = *(const float4*)(row + 4 * q);
            ylds[(4 * q + 0) * 256 + tid] = v.x;
            ylds[(4 * q + 1) * 256 + tid] = v.y;
            ylds[(4 * q + 2) * 256 + tid] = v.z;
            ylds[(4 * q + 3) * 256 + tid] = v.w;
        }
    }

    const float* g1 = g1g + (size_t)b * 2 * NPIX;
    const float* g2 = g2g + (size_t)b * 2 * NPIX;
    int i = i0 + wv;
    float g1y = g1[i];
    float g1x = g1[NPIX + i];

    // bin = norm(grid[...,1,1] - grid[...,0,0])  (bit-exact chain)
    const float* gb = loss ? g2 : g1;
    float d0  = gb[29] - gb[0];
    float d1  = gb[NPIX + 29] - gb[NPIX];
    float bin = __fsqrt_rn(__fadd_rn(__fmul_rn(d0, d0), __fmul_rn(d1, d1)));

    // candidate box in grid2 index space (guard-widened superset; exact below)
    float t2y = g2[0], t2x = g2[NPIX];
    float s2y = g2[28] - g2[0];
    float s2x = g2[NPIX + 1] - g2[NPIX];
    float r  = 0.7f * bin * 1.0002f + 1e-4f;
    float cy = (g1y - t2y) / s2y;
    float cx = (g1x - t2x) / s2x;
    float ry = r / s2y + 0.05f;
    float rx = r / s2x + 0.05f;
    int jy0 = max(0,  (int)ceilf(cy - ry));
    int jy1 = min(27, (int)floorf(cy + ry));
    int jx0 = max(0,  (int)ceilf(cx - rx));
    int jx1 = min(27, (int)floorf(cx + rx));
    int dyr = jy1 - jy0, dxr = jx1 - jx0;

    int dyl = lane >> 2, dxl = lane & 3;
    bool pass = false;
    if (lane < 16 && dyl <= dyr && dxl <= dxr) {
        int jc = (jy0 + dyl) * 28 + jx0 + dxl;
        float dy = g1y - g2[jc];
        float dx = g1x - g2[NPIX + jc];
        float d  = __fsqrt_rn(__fadd_rn(__fmul_rn(dy, dy), __fmul_rn(dx, dx)));
        pass = (__fdiv_rn(d, bin) <= 0.7f);   // bit-exact mask decision
    }
    unsigned long long m = __ballot(pass);
    int cnt = __builtin_popcountll(m);

    __syncthreads();

    int gl = lane & 15, g = lane >> 4;
    const float4* Yr = (const float4*)(ylds + wv * 256);
    float4 ya = Yr[gl], yb = Yr[gl + 16], yc = Yr[gl + 32], yd = Yr[gl + 48];

    // na from registers (16-lane group reduce)
    float p = ya.x * ya.x;
    p = fmaf(ya.y, ya.y, p); p = fmaf(ya.z, ya.z, p); p = fmaf(ya.w, ya.w, p);
    p = fmaf(yb.x, yb.x, p); p = fmaf(yb.y, yb.y, p); p = fmaf(yb.z, yb.z, p);
    p = fmaf(yb.w, yb.w, p);
    p = fmaf(yc.x, yc.x, p); p = fmaf(yc.y, yc.y, p); p = fmaf(yc.z, yc.z, p);
    p = fmaf(yc.w, yc.w, p);
    p = fmaf(yd.x, yd.x, p); p = fmaf(yd.y, yd.y, p); p = fmaf(yd.z, yd.z, p);
    p = fmaf(yd.w, yd.w, p);
#pragma unroll
    for (int off = 1; off < 16; off <<= 1) p += __shfl_xor(p, off);
    float na = __fsqrt_rn(p);

    const float* Zb = zt  + ((size_t)(1 - loss) * BB + b) * ((size_t)NPIX * CC);
    const float* zn = zn2 + ((size_t)(1 - loss) * BB + b) * NPIX;

    // compact-slot rounds: group g walks the (4r+g)-th SET bit of m.
    unsigned mm = (unsigned)m;
    if (g > 0) mm &= mm - 1;
    if (g > 1) mm &= mm - 1;
    if (g > 2) mm &= mm - 1;
    int rounds = (cnt + 3) >> 2;             // wave-uniform

    double ssum = 0.0;
    for (int r2 = 0; r2 < rounds; r2++) {
        if (mm) {                            // exec-mask skip: no dummy loads
            int s = __ffs(mm) - 1;           // this group's slot (set bit)
            int j = (jy0 + (s >> 2)) * 28 + jx0 + (s & 3);
            const float4* Z4 = (const float4*)(Zb + (size_t)j * CC);
            float4 za = Z4[gl], zb_ = Z4[gl + 16], zc = Z4[gl + 32], zd = Z4[gl + 48];
            float nb2 = zn[j];
            float dp = ya.x * za.x;
            dp = fmaf(ya.y, za.y, dp); dp = fmaf(ya.z, za.z, dp);
            dp = fmaf(ya.w, za.w, dp);
            dp = fmaf(yb.x, zb_.x, dp); dp = fmaf(yb.y, zb_.y, dp);
            dp = fmaf(yb.z, zb_.z, dp); dp = fmaf(yb.w, zb_.w, dp);
            dp = fmaf(yc.x, zc.x, dp); dp = fmaf(yc.y, zc.y, dp);
            dp = fmaf(yc.z, zc.z, dp); dp = fmaf(yc.w, zc.w, dp);
            dp = fmaf(yd.x, zd.x, dp); dp = fmaf(yd.y, zd.y, dp);
            dp = fmaf(yd.z, zd.z, dp); dp = fmaf(yd.w, zd.w, dp);
            float den = fmaxf(na * __fsqrt_rn(nb2), 1e-8f);
            ssum += (double)__fdividef(dp, den);   // per-lane partial / den
        }
        mm &= mm - 1; mm &= mm - 1; mm &= mm - 1; mm &= mm - 1;
    }
    // one 64-lane double butterfly per wave (was 4 shuffles per round)
#pragma unroll
    for (int off = 1; off < 64; off <<= 1) ssum += __shfl_xor(ssum, off);

    if (lane == 0) { shs[wv] = ssum; shc[wv] = cnt; }
    __syncthreads();
    if (tid == 0) {
        double s = 0.0; int c = 0;
#pragma unroll
        for (int k = 0; k < 16; k++) { s += shs[k]; c += shc[k]; }
        double* slot = acc + (size_t)(bx & (SLOTS - 1)) * 4;
        atomicAdd(&slot[loss * 2],     s);
        atomicAdd(&slot[loss * 2 + 1], (double)c);
    }
}

// ---------------------------------------------------------------------------
// K3: finalize  loss = -(S0/M0 + S1/M1)  (reduce the 128 slots)
// ---------------------------------------------------------------------------
__global__ void fin_k(const double* __restrict__ acc, float* __restrict__ out) {
    int lane = threadIdx.x;   // 64 threads
    double s0 = 0, m0 = 0, s1 = 0, m1 = 0;
    for (int s = lane; s < SLOTS; s += 64) {
        const double* p = acc + (size_t)s * 4;
        s0 += p[0]; m0 += p[1]; s1 += p[2]; m1 += p[3];
    }
#pragma unroll
    for (int off = 32; off; off >>= 1) {
        s0 += __shfl_xor(s0, off); m0 += __shfl_xor(m0, off);
        s1 += __shfl_xor(s1, off); m1 += __shfl_xor(m1, off);
    }
    if (lane == 0) out[0] = (float)(-(s0 / m0 + s1 / m1));
}

extern "C" void kernel_launch(void* const* d_in, const int* in_sizes, int n_in,
                              void* d_out, int out_size, void* d_ws, size_t ws_size,
                              hipStream_t stream) {
    const float* y1 = (const float*)d_in[0];
    const float* y2 = (const float*)d_in[1];
    const float* z1 = (const float*)d_in[2];
    const float* z2 = (const float*)d_in[3];
    const float* g1 = (const float*)d_in[4];
    const float* g2 = (const float*)d_in[5];
    float* out = (float*)d_out;

    char* ws = (char*)d_ws;
    double* acc = (double*)ws;                         // SLOTS*4 doubles = 4 KB
    float*  zn2 = (float*)(ws + 4096);                 // 2*BNP floats
    float*  zt  = (float*)(ws + 4096 + 2 * BNP * sizeof(float));
    // zt: [2][B][N][C] = 2 * 12,845,056 floats = 102.8 MB

    hipMemsetAsync(acc, 0, SLOTS * 4 * sizeof(double), stream);

    // z transpose + norms: 2 arrays * 64 b * 25 n-tiles = 3200 blocks
    zt_k<<<3200, 512, 0, stream>>>(z1, z2, zt, zn2);

    // pairs: 2 losses * 64 b * 49 i-groups = 6272 blocks x 1024 threads
    pairs_k<<<6272, 1024, 0, stream>>>(y1, y2, zt, zn2, g1, g2, acc);

    fin_k<<<1, 64, 0, stream>>>(acc, out);
}